// Round 5
// baseline (326.393 us; speedup 1.0000x reference)
//
#include <hip/hip_runtime.h>

typedef __attribute__((ext_vector_type(8))) short short8;
typedef __attribute__((ext_vector_type(4))) float f32x4;
typedef __attribute__((ext_vector_type(2))) unsigned u32x2;
typedef __attribute__((ext_vector_type(4))) unsigned u32x4;

#define SCL2 0.18033688011112042f   /* 64^-0.5 * log2(e), folded into Q */

__device__ __forceinline__ unsigned pk2(float lo, float hi) {
  unsigned r;
  asm("v_cvt_pk_bf16_f32 %0, %1, %2" : "=v"(r) : "v"(lo), "v"(hi));
  return r;
}

__device__ __forceinline__ short8 pk8(float4 a, float4 b) {
  u32x4 u = { pk2(a.x, a.y), pk2(a.z, a.w), pk2(b.x, b.y), pk2(b.z, b.w) };
  return __builtin_bit_cast(short8, u);
}

__global__ __launch_bounds__(256, 4)
void lattn(const float* __restrict__ Qg, const float* __restrict__ Kg,
           const float* __restrict__ Vg, float* __restrict__ Og) {
  constexpr int S = 8192, H = 16, RS = H * 64;   // row stride in floats
  __shared__ __align__(16) unsigned char smem[32768];
  unsigned char* Klds = smem;            // [64 k][64 d] bf16, chunk-XOR swizzled (8 KB)
  unsigned char* Vlds = smem + 8192;     // [64 d][64 k] bf16 (transposed), swizzled (8 KB)

  const int tid = threadIdx.x;
  const int l = tid & 63, w = tid >> 6, g = l >> 4, l15 = l & 15;
  unsigned char* Plds = smem + 16384 + w * 4096;  // per-wave [32 q][64 k] bf16 (4 KB)

  // bijective XCD swizzle: adjacent q-blocks (sharing K/V) land on the same XCD
  const int wg = ((blockIdx.x & 7) << 8) + (blockIdx.x >> 3);   // 2048 % 8 == 0
  const int n = wg & 63, h = (wg >> 6) & 15, b = wg >> 10;

  const float* Qp = Qg + (size_t)b * S * RS + h * 64;
  const float* Kp = Kg + (size_t)b * S * RS + h * 64;
  const float* Vp = Vg + (size_t)b * S * RS + h * 64;
  float*       Op = Og + (size_t)b * S * RS + h * 64;

  const int wq0 = 32 * w;            // wave's first q row within the 128-row block
  const int qg0 = n * 128 + wq0;

  // ---- Q fragments in registers, pre-scaled by SCL2: q = 16*nr+l15, d = g*8+32*ks..+7
  short8 qf[2][2];
#pragma unroll
  for (int nr = 0; nr < 2; ++nr) {
    const float* qrow = Qp + (size_t)(qg0 + 16 * nr + l15) * RS;
#pragma unroll
    for (int ks = 0; ks < 2; ++ks) {
      float4 a = *(const float4*)(qrow + g * 8 + 32 * ks);
      float4 c = *(const float4*)(qrow + g * 8 + 32 * ks + 4);
      a.x *= SCL2; a.y *= SCL2; a.z *= SCL2; a.w *= SCL2;
      c.x *= SCL2; c.y *= SCL2; c.z *= SCL2; c.w *= SCL2;
      qf[ks][nr] = pk8(a, c);
    }
  }

  f32x4 acc[2][4];                   // [q-16-tile][d-16-tile]
#pragma unroll
  for (int i = 0; i < 2; ++i)
#pragma unroll
    for (int j = 0; j < 4; ++j) acc[i][j] = f32x4{0.f, 0.f, 0.f, 0.f};
  float m_run[2] = {-1e20f, -1e20f};
  float l_run[2] = {0.f, 0.f};

  const int kvb = n * 128 - 256;                      // 64-aligned, may be <0 for n<2
  const int t0 = (n == 0) ? 4 : ((n == 1) ? 2 : 0);   // skip tiles before row 0

  for (int t = t0; t < 6; ++t) {
    __syncthreads();                 // protect K/V LDS from previous phase's readers
    // ---- stage K tile (row-major bf16, swizzled)
#pragma unroll
    for (int cc = 0; cc < 2; ++cc) {
      int cid = tid + (cc << 8);
      int r = cid >> 3, ch = cid & 7;
      const float* src = Kp + (size_t)(kvb + t * 64 + r) * RS + ch * 8;
      float4 a = *(const float4*)(src);
      float4 c = *(const float4*)(src + 4);
      *(short8*)(Klds + r * 128 + ((ch ^ (r & 7)) << 4)) = pk8(a, c);
    }
    // ---- stage V transposed ([d][k] bf16, swizzled)
#pragma unroll
    for (int cc = 0; cc < 2; ++cc) {
      int cid = tid + (cc << 8);
      int d = cid & 63, kc = cid >> 6;   // kc 0..3 then 4..7
      const float* src = Vp + (size_t)(kvb + t * 64 + kc * 8) * RS + d;
      float f0 = src[0], f1 = src[RS], f2 = src[2 * RS], f3 = src[3 * RS];
      float f4 = src[4 * RS], f5 = src[5 * RS], f6 = src[6 * RS], f7 = src[7 * RS];
      u32x4 u = { pk2(f0, f1), pk2(f2, f3), pk2(f4, f5), pk2(f6, f7) };
      *(short8*)(Vlds + d * 128 + ((kc ^ (d & 7)) << 4)) = __builtin_bit_cast(short8, u);
    }
    __syncthreads();

    // wave-uniform activity: does [64t,64t+63] overlap (wq0, wq0+31+256] ?
    if (64 * t + 63 > wq0 && 64 * t <= wq0 + 287) {
      const bool noMask = (64 * t >= wq0 + 32) && (64 * t + 63 <= wq0 + 256);

      // ---- S^T = K·Q^T (rows k, cols q)
      f32x4 s[4][2];
#pragma unroll
      for (int i = 0; i < 4; ++i)
#pragma unroll
        for (int j = 0; j < 2; ++j) s[i][j] = f32x4{0.f, 0.f, 0.f, 0.f};
#pragma unroll
      for (int ks = 0; ks < 2; ++ks) {
        short8 kf[4];
#pragma unroll
        for (int mr = 0; mr < 4; ++mr) {
          int r = mr * 16 + l15;
          kf[mr] = *(const short8*)(Klds + r * 128 + (((g + 4 * ks) ^ (r & 7)) << 4));
        }
#pragma unroll
        for (int mr = 0; mr < 4; ++mr)
#pragma unroll
          for (int nr = 0; nr < 2; ++nr)
            s[mr][nr] = __builtin_amdgcn_mfma_f32_16x16x32_bf16(kf[mr], qf[ks][nr],
                                                                s[mr][nr], 0, 0, 0);
      }

      // ---- online softmax (log2 domain; scale already folded into Q)
      float corrv[2];
#pragma unroll
      for (int nr = 0; nr < 2; ++nr) {
        int q = wq0 + 16 * nr + l15;
        float mx = -3e38f;
        if (noMask) {
#pragma unroll
          for (int mr = 0; mr < 4; ++mr)
#pragma unroll
            for (int reg = 0; reg < 4; ++reg) mx = fmaxf(mx, s[mr][nr][reg]);
        } else {
#pragma unroll
          for (int mr = 0; mr < 4; ++mr)
#pragma unroll
            for (int reg = 0; reg < 4; ++reg) {
              int koff = 64 * t + 16 * mr + 4 * g + reg;
              bool valid = (koff > q) && (koff <= q + 256);
              float sv = valid ? s[mr][nr][reg] : -1e30f;
              s[mr][nr][reg] = sv;
              mx = fmaxf(mx, sv);
            }
        }
        mx = fmaxf(mx, __shfl_xor(mx, 16));
        mx = fmaxf(mx, __shfl_xor(mx, 32));
        float mnew = fmaxf(m_run[nr], mx);
        float corr = exp2f(m_run[nr] - mnew);
        m_run[nr] = mnew;
        float sum = 0.f;
#pragma unroll
        for (int mr = 0; mr < 4; ++mr)
#pragma unroll
          for (int reg = 0; reg < 4; ++reg) {
            float p = exp2f(s[mr][nr][reg] - mnew);
            s[mr][nr][reg] = p;
            sum += p;
          }
        sum += __shfl_xor(sum, 16);
        sum += __shfl_xor(sum, 32);
        l_run[nr] = l_run[nr] * corr + sum;
        corrv[nr] = corr;
      }
      // ---- rescale O (corr lives at lane l15 = q-in-tile; acc row = 4g+reg)
#pragma unroll
      for (int mq = 0; mq < 2; ++mq)
#pragma unroll
        for (int reg = 0; reg < 4; ++reg) {
          float c = __shfl(corrv[mq], 4 * g + reg, 16);
#pragma unroll
          for (int nd = 0; nd < 4; ++nd) acc[mq][nd][reg] *= c;
        }
      // ---- P → per-wave LDS [32 q][64 k] bf16, swizzled
#pragma unroll
      for (int nr = 0; nr < 2; ++nr)
#pragma unroll
        for (int mr = 0; mr < 4; ++mr) {
          int q = 16 * nr + l15;
          int cb = 2 * mr + (g >> 1);
          int off = q * 128 + ((cb ^ (q & 7)) << 4) + ((g & 1) << 3);
          u32x2 pw = { pk2(s[mr][nr][0], s[mr][nr][1]),
                       pk2(s[mr][nr][2], s[mr][nr][3]) };
          *(u32x2*)(Plds + off) = pw;
        }
      asm volatile("s_waitcnt lgkmcnt(0)" ::: "memory");  // within-wave cross-lane RAW

      // ---- O += P·V  (A rows = q, B rows = d, contiguous b128 reads)
#pragma unroll
      for (int ks = 0; ks < 2; ++ks) {
        short8 pf[2], vf[4];
#pragma unroll
        for (int mq = 0; mq < 2; ++mq) {
          int q = 16 * mq + l15;
          pf[mq] = *(const short8*)(Plds + q * 128 + (((g + 4 * ks) ^ (q & 7)) << 4));
        }
#pragma unroll
        for (int nd = 0; nd < 4; ++nd) {
          int d = 16 * nd + l15;
          vf[nd] = *(const short8*)(Vlds + d * 128 + (((g + 4 * ks) ^ (d & 7)) << 4));
        }
#pragma unroll
        for (int mq = 0; mq < 2; ++mq)
#pragma unroll
          for (int nd = 0; nd < 4; ++nd)
            acc[mq][nd] = __builtin_amdgcn_mfma_f32_16x16x32_bf16(pf[mq], vf[nd],
                                                                  acc[mq][nd], 0, 0, 0);
      }
    }
  }

  // ---- finalize
  float linv[2] = {1.0f / l_run[0], 1.0f / l_run[1]};
#pragma unroll
  for (int mq = 0; mq < 2; ++mq)
#pragma unroll
    for (int reg = 0; reg < 4; ++reg) {
      float li = __shfl(linv[mq], 4 * g + reg, 16);
      int qrow = qg0 + 16 * mq + 4 * g + reg;
      float* orow = Op + (size_t)qrow * RS;
#pragma unroll
      for (int nd = 0; nd < 4; ++nd)
        orow[16 * nd + l15] = acc[mq][nd][reg] * li;
    }
}

extern "C" void kernel_launch(void* const* d_in, const int* in_sizes, int n_in,
                              void* d_out, int out_size, void* d_ws, size_t ws_size,
                              hipStream_t stream) {
  (void)in_sizes; (void)n_in; (void)d_ws; (void)ws_size; (void)out_size;
  const float* q = (const float*)d_in[0];
  const float* k = (const float*)d_in[1];
  const float* v = (const float*)d_in[2];
  float* o = (float*)d_out;
  dim3 grid(2 * 16 * 64);   // B * H * (8192/128) = 2048 workgroups
  dim3 block(256);
  lattn<<<grid, block, 0, stream>>>(q, k, v, o);
}

// Round 6
// 254.221 us; speedup vs baseline: 1.2839x; 1.2839x over previous
//
#include <hip/hip_runtime.h>

typedef __attribute__((ext_vector_type(8))) short short8;
typedef __attribute__((ext_vector_type(4))) float f32x4;
typedef __attribute__((ext_vector_type(2))) unsigned u32x2;
typedef __attribute__((ext_vector_type(4))) unsigned u32x4;

#define SCL2 0.18033688011112042f   /* 64^-0.5 * log2(e), folded into Q */

__device__ __forceinline__ unsigned pk2(float lo, float hi) {
  unsigned r;
  asm("v_cvt_pk_bf16_f32 %0, %1, %2" : "=v"(r) : "v"(lo), "v"(hi));
  return r;
}

__device__ __forceinline__ short8 pk8(float4 a, float4 b) {
  u32x4 u = { pk2(a.x, a.y), pk2(a.z, a.w), pk2(b.x, b.y), pk2(b.z, b.w) };
  return __builtin_bit_cast(short8, u);
}

__global__ __launch_bounds__(256, 3)   // 3 waves/EU: unified-file cap ~170/wave -> no spill
void lattn(const float* __restrict__ Qg, const float* __restrict__ Kg,
           const float* __restrict__ Vg, float* __restrict__ Og) {
  constexpr int S = 8192, H = 16, RS = H * 64;   // row stride in floats
  __shared__ __align__(16) unsigned char smem[32768];
  unsigned char* Klds = smem;            // [64 k][64 d] bf16, chunk-XOR swizzled (8 KB)
  unsigned char* Vlds = smem + 8192;     // [64 d][64 k] bf16 (transposed), swizzled (8 KB)

  const int tid = threadIdx.x;
  const int l = tid & 63, w = tid >> 6, g = l >> 4, l15 = l & 15;
  unsigned char* Plds = smem + 16384 + w * 4096;  // per-wave [32 q][64 k] bf16 (4 KB)

  // bijective XCD swizzle: adjacent q-blocks (sharing K/V) land on the same XCD
  const int wg = ((blockIdx.x & 7) << 8) + (blockIdx.x >> 3);   // 2048 % 8 == 0
  const int n = wg & 63, h = (wg >> 6) & 15, b = wg >> 10;

  const float* Qp = Qg + (size_t)b * S * RS + h * 64;
  const float* Kp = Kg + (size_t)b * S * RS + h * 64;
  const float* Vp = Vg + (size_t)b * S * RS + h * 64;
  float*       Op = Og + (size_t)b * S * RS + h * 64;

  const int wq0 = 32 * w;            // wave's first q row within the 128-row block
  const int qg0 = n * 128 + wq0;

  // ---- Q fragments in registers, pre-scaled by SCL2: q = 16*nr+l15, d = g*8+32*ks..+7
  short8 qf[2][2];
#pragma unroll
  for (int nr = 0; nr < 2; ++nr) {
    const float* qrow = Qp + (size_t)(qg0 + 16 * nr + l15) * RS;
#pragma unroll
    for (int ks = 0; ks < 2; ++ks) {
      float4 a = *(const float4*)(qrow + g * 8 + 32 * ks);
      float4 c = *(const float4*)(qrow + g * 8 + 32 * ks + 4);
      a.x *= SCL2; a.y *= SCL2; a.z *= SCL2; a.w *= SCL2;
      c.x *= SCL2; c.y *= SCL2; c.z *= SCL2; c.w *= SCL2;
      qf[ks][nr] = pk8(a, c);
    }
  }

  f32x4 acc[2][4];                   // [q-16-tile][d-16-tile]
#pragma unroll
  for (int i = 0; i < 2; ++i)
#pragma unroll
    for (int j = 0; j < 4; ++j) acc[i][j] = f32x4{0.f, 0.f, 0.f, 0.f};
  float m_run[2] = {-1e20f, -1e20f};
  float l_run[2] = {0.f, 0.f};

  const int kvb = n * 128 - 256;                      // 64-aligned, may be <0 for n<2
  const int t0 = (n == 0) ? 4 : ((n == 1) ? 2 : 0);   // skip tiles before row 0

  for (int t = t0; t < 6; ++t) {
    __syncthreads();                 // protect K/V LDS from previous phase's readers
    // ---- stage K tile (row-major bf16, swizzled)
#pragma unroll
    for (int cc = 0; cc < 2; ++cc) {
      int cid = tid + (cc << 8);
      int r = cid >> 3, ch = cid & 7;
      const float* src = Kp + (size_t)(kvb + t * 64 + r) * RS + ch * 8;
      float4 a = *(const float4*)(src);
      float4 c = *(const float4*)(src + 4);
      *(short8*)(Klds + r * 128 + ((ch ^ (r & 7)) << 4)) = pk8(a, c);
    }
    // ---- stage V transposed ([d][k] bf16, swizzled)
#pragma unroll
    for (int cc = 0; cc < 2; ++cc) {
      int cid = tid + (cc << 8);
      int d = cid & 63, kc = cid >> 6;   // kc 0..3 then 4..7
      const float* src = Vp + (size_t)(kvb + t * 64 + kc * 8) * RS + d;
      float f0 = src[0], f1 = src[RS], f2 = src[2 * RS], f3 = src[3 * RS];
      float f4 = src[4 * RS], f5 = src[5 * RS], f6 = src[6 * RS], f7 = src[7 * RS];
      u32x4 u = { pk2(f0, f1), pk2(f2, f3), pk2(f4, f5), pk2(f6, f7) };
      *(short8*)(Vlds + d * 128 + ((kc ^ (d & 7)) << 4)) = __builtin_bit_cast(short8, u);
    }
    __syncthreads();

    // wave-uniform activity: does [64t,64t+63] overlap (wq0, wq0+31+256] ?
    if (64 * t + 63 > wq0 && 64 * t <= wq0 + 287) {
      const bool noMask = (64 * t >= wq0 + 32) && (64 * t + 63 <= wq0 + 256);

      // ---- S^T = K·Q^T (rows k, cols q)
      f32x4 s[4][2];
#pragma unroll
      for (int i = 0; i < 4; ++i)
#pragma unroll
        for (int j = 0; j < 2; ++j) s[i][j] = f32x4{0.f, 0.f, 0.f, 0.f};
#pragma unroll
      for (int ks = 0; ks < 2; ++ks) {
        short8 kf[4];
#pragma unroll
        for (int mr = 0; mr < 4; ++mr) {
          int r = mr * 16 + l15;
          kf[mr] = *(const short8*)(Klds + r * 128 + (((g + 4 * ks) ^ (r & 7)) << 4));
        }
#pragma unroll
        for (int mr = 0; mr < 4; ++mr)
#pragma unroll
          for (int nr = 0; nr < 2; ++nr)
            s[mr][nr] = __builtin_amdgcn_mfma_f32_16x16x32_bf16(kf[mr], qf[ks][nr],
                                                                s[mr][nr], 0, 0, 0);
      }

      // ---- online softmax (log2 domain; scale already folded into Q)
      float corrv[2];
#pragma unroll
      for (int nr = 0; nr < 2; ++nr) {
        int q = wq0 + 16 * nr + l15;
        float mx = -3e38f;
        if (noMask) {
#pragma unroll
          for (int mr = 0; mr < 4; ++mr)
#pragma unroll
            for (int reg = 0; reg < 4; ++reg) mx = fmaxf(mx, s[mr][nr][reg]);
        } else {
#pragma unroll
          for (int mr = 0; mr < 4; ++mr)
#pragma unroll
            for (int reg = 0; reg < 4; ++reg) {
              int koff = 64 * t + 16 * mr + 4 * g + reg;
              bool valid = (koff > q) && (koff <= q + 256);
              float sv = valid ? s[mr][nr][reg] : -1e30f;
              s[mr][nr][reg] = sv;
              mx = fmaxf(mx, sv);
            }
        }
        mx = fmaxf(mx, __shfl_xor(mx, 16));
        mx = fmaxf(mx, __shfl_xor(mx, 32));
        float mnew = fmaxf(m_run[nr], mx);
        float corr = exp2f(m_run[nr] - mnew);
        m_run[nr] = mnew;
        float sum = 0.f;
#pragma unroll
        for (int mr = 0; mr < 4; ++mr)
#pragma unroll
          for (int reg = 0; reg < 4; ++reg) {
            float p = exp2f(s[mr][nr][reg] - mnew);
            s[mr][nr][reg] = p;
            sum += p;
          }
        sum += __shfl_xor(sum, 16);
        sum += __shfl_xor(sum, 32);
        l_run[nr] = l_run[nr] * corr + sum;
        corrv[nr] = corr;
      }
      // ---- P → per-wave LDS [32 q][64 k] bf16, swizzled (ends s's lifetime)
#pragma unroll
      for (int nr = 0; nr < 2; ++nr)
#pragma unroll
        for (int mr = 0; mr < 4; ++mr) {
          int q = 16 * nr + l15;
          int cb = 2 * mr + (g >> 1);
          int off = q * 128 + ((cb ^ (q & 7)) << 4) + ((g & 1) << 3);
          u32x2 pw = { pk2(s[mr][nr][0], s[mr][nr][1]),
                       pk2(s[mr][nr][2], s[mr][nr][3]) };
          *(u32x2*)(Plds + off) = pw;
        }
      // ---- rescale O while the P ds_writes drain
      // (corr lives at lane l15 = q-in-tile; acc row = 4g+reg)
#pragma unroll
      for (int mq = 0; mq < 2; ++mq)
#pragma unroll
        for (int reg = 0; reg < 4; ++reg) {
          float c = __shfl(corrv[mq], 4 * g + reg, 16);
#pragma unroll
          for (int nd = 0; nd < 4; ++nd) acc[mq][nd][reg] *= c;
        }
      asm volatile("s_waitcnt lgkmcnt(0)" ::: "memory");  // within-wave cross-lane RAW

      // ---- O += P·V  (A rows = q, B rows = d, contiguous b128 reads)
#pragma unroll
      for (int ks = 0; ks < 2; ++ks) {
        short8 pf[2], vf[4];
#pragma unroll
        for (int mq = 0; mq < 2; ++mq) {
          int q = 16 * mq + l15;
          pf[mq] = *(const short8*)(Plds + q * 128 + (((g + 4 * ks) ^ (q & 7)) << 4));
        }
#pragma unroll
        for (int nd = 0; nd < 4; ++nd) {
          int d = 16 * nd + l15;
          vf[nd] = *(const short8*)(Vlds + d * 128 + (((g + 4 * ks) ^ (d & 7)) << 4));
        }
#pragma unroll
        for (int mq = 0; mq < 2; ++mq)
#pragma unroll
          for (int nd = 0; nd < 4; ++nd)
            acc[mq][nd] = __builtin_amdgcn_mfma_f32_16x16x32_bf16(pf[mq], vf[nd],
                                                                  acc[mq][nd], 0, 0, 0);
      }
    }
  }

  // ---- finalize
  float linv[2] = {1.0f / l_run[0], 1.0f / l_run[1]};
#pragma unroll
  for (int mq = 0; mq < 2; ++mq)
#pragma unroll
    for (int reg = 0; reg < 4; ++reg) {
      float li = __shfl(linv[mq], 4 * g + reg, 16);
      int qrow = qg0 + 16 * mq + 4 * g + reg;
      float* orow = Op + (size_t)qrow * RS;
#pragma unroll
      for (int nd = 0; nd < 4; ++nd)
        orow[16 * nd + l15] = acc[mq][nd][reg] * li;
    }
}

extern "C" void kernel_launch(void* const* d_in, const int* in_sizes, int n_in,
                              void* d_out, int out_size, void* d_ws, size_t ws_size,
                              hipStream_t stream) {
  (void)in_sizes; (void)n_in; (void)d_ws; (void)ws_size; (void)out_size;
  const float* q = (const float*)d_in[0];
  const float* k = (const float*)d_in[1];
  const float* v = (const float*)d_in[2];
  float* o = (float*)d_out;
  dim3 grid(2 * 16 * 64);   // B * H * (8192/128) = 2048 workgroups
  dim3 block(256);
  lattn<<<grid, block, 0, stream>>>(q, k, v, o);
}